// Round 12
// baseline (500.075 us; speedup 1.0000x reference)
//
#include <hip/hip_runtime.h>

#define NV 400000
#define KOFF 27
#define CD 64
#define DD 128
#define HH 128
#define WW 128
#define TABN (2*DD*HH*WW)
#define NCELL 32768
#define EPSV 1e-5f

typedef _Float16 f16;
typedef _Float16 f16x8 __attribute__((ext_vector_type(8)));
typedef float f32x16 __attribute__((ext_vector_type(16)));

// ---- workspace layout (bytes) ----
#define OFF_NBR   0ull
#define OFF_X1    43200000ull
#define OFF_X2    94400000ull
#define OFF_TAB   94400000ull     // table dead before x2 written
#define OFF_HIST  111177216ull    // 32K rows * 4B, inside x2 region (dead pre-conv2)
#define OFF_BSUM  111308288ull    // 32 block sums for 2-level scan
#define OFF_FS    111439360ull    // sorted feats, 1.6MB, inside x2 region (dead pre-conv2)
#define OFF_W2T   145600000ull
#define OFF_W3T   145821184ull
#define OFF_ZERO  146042368ull

#define GLDS16(gp, lp) __builtin_amdgcn_global_load_lds( \
    (__attribute__((address_space(1))) void*)(gp), \
    (__attribute__((address_space(3))) void*)(lp), 16, 0, 0)

// ROW-major buckets (b,z,y): ~12.2 voxels/bucket share the same 9
// neighbor-row line sets -> locality for tab reads and conv gathers.
__device__ __forceinline__ int cell_of(int4 c) {
    return (c.x * DD + c.y) * HH + c.z;    // (b*128+z)*128+y, < 32768
}

// ---- init: table=-1; hist=0; weights -> f16 chunk-major wTg[k][cin/8][cout][cin&7]
__global__ void k_init(const float* __restrict__ w2, const float* __restrict__ w3,
                       int* __restrict__ tab, f16* __restrict__ w2t,
                       f16* __restrict__ w3t, f16* __restrict__ zrow,
                       int* __restrict__ hist) {
    int t = blockIdx.x * 256 + threadIdx.x;           // grid: 4096*256
    int4* tv = (int4*)tab;
    if (t < TABN / 4) tv[t] = make_int4(-1, -1, -1, -1);
    if (t < NCELL) hist[t] = 0;
    if (t < KOFF * CD * CD) {
        int k = t >> 12, r = t & 4095, c = r >> 6, ci = r & 63;
        int d = (k << 12) + ((ci >> 3) << 9) + (c << 3) + (ci & 7);
        w2t[d] = (f16)w2[(k << 12) + (ci << 6) + c];
        w3t[d] = (f16)w3[(k << 12) + (ci << 6) + c];
    }
    if (t < CD) zrow[t] = (f16)0.f;
}

// ---- spatial counting-sort: hist -> 2-level scan -> rank assignment ----
__global__ void k_hist(const int4* __restrict__ coords, int* __restrict__ hist) {
    int i = blockIdx.x * 256 + threadIdx.x;
    if (i >= NV) return;
    atomicAdd(&hist[cell_of(coords[i])], 1);
}

// level 1: 32 blocks x 1024 threads, COALESCED loads (old single-WG scan had
// every lane on its own line: base=t*32). Exclusive-in-block + block total.
__global__ __launch_bounds__(1024) void k_scan1(int* __restrict__ hist,
                                                int* __restrict__ bsum) {
    __shared__ int sm[1024];
    int b = blockIdx.x;
    int t = threadIdx.x;
    int idx = b * 1024 + t;
    int v = hist[idx];
    sm[t] = v;
    __syncthreads();
    for (int off = 1; off < 1024; off <<= 1) {
        int u = (t >= off) ? sm[t - off] : 0;
        __syncthreads();
        sm[t] += u;
        __syncthreads();
    }
    hist[idx] = sm[t] - v;            // exclusive within block
    if (t == 1023) bsum[b] = sm[t];   // block total
}

// level 2: exclusive scan of the 32 block totals
__global__ void k_scan2(int* __restrict__ bsum) {
    if (threadIdx.x == 0 && blockIdx.x == 0) {
        int acc = 0;
        #pragma unroll
        for (int i = 0; i < 32; i++) { int h = bsum[i]; bsum[i] = acc; acc += h; }
    }
}

// rank r = row-contiguous position (in-block base + block offset). Writes:
//   tab[site] = r; nbr[13*NV+r] = orig index; feats_s[r] = feats[orig]
__global__ void k_rank(const int4* __restrict__ coords, const float* __restrict__ feats,
                       int* __restrict__ hist, const int* __restrict__ bsum,
                       int* __restrict__ tab, int* __restrict__ nbr,
                       float* __restrict__ feats_s) {
    int i = blockIdx.x * 256 + threadIdx.x;
    if (i >= NV) return;
    int4 c = coords[i];
    int cell = cell_of(c);
    int r = atomicAdd(&hist[cell], 1) + bsum[cell >> 10];
    int flat = ((c.x * DD + c.y) * HH + c.z) * WW + c.w;
    tab[flat] = r;
    nbr[13 * (size_t)NV + r] = i;
    feats_s[r] = feats[i];
}

// ---- FUSED rulebook + layer 1: compute idx once, write nbr[k] for the convs,
// and immediately consume it for layer-1's 64-wide FMA. Kills the 43 MB
// nbr round-trip the old k_nbr2 -> k_layer1 pair paid. k=13: idx = r (self),
// nbr[13] slot NOT overwritten (holds orig index for the final scatter-back).
__global__ __launch_bounds__(256) void k_nbrl1(
        const int4* __restrict__ coords, const int* __restrict__ tab,
        const float* __restrict__ feats_s, int* __restrict__ nbr,
        const float* __restrict__ w1, const float* __restrict__ b1,
        const float* __restrict__ g1, const float* __restrict__ be1,
        const float* __restrict__ m1, const float* __restrict__ v1,
        f16* __restrict__ x1) {
    int r = blockIdx.x * 256 + threadIdx.x;   // r = rank
    if (r >= NV) return;
    int orig = nbr[13 * (size_t)NV + r];
    int4 c = coords[orig];

    float acc[CD];
    #pragma unroll
    for (int cc = 0; cc < CD; cc++) acc[cc] = 0.f;

    int k = 0;
    #pragma unroll
    for (int dz = -1; dz <= 1; dz++)
    #pragma unroll
    for (int dy = -1; dy <= 1; dy++)
    #pragma unroll
    for (int dx = -1; dx <= 1; dx++) {
        int idx;
        if (k == 13) {
            idx = r;
        } else {
            int z = c.y + dz, y = c.z + dy, x = c.w + dx;
            idx = -1;
            if (z >= 0 && z < DD && y >= 0 && y < HH && x >= 0 && x < WW)
                idx = tab[((c.x * DD + z) * HH + y) * WW + x];
            nbr[(size_t)k * NV + r] = idx;
        }
        float fk = (idx >= 0) ? feats_s[idx] : 0.f;
        #pragma unroll
        for (int cc = 0; cc < CD; cc++)
            acc[cc] = fmaf(fk, w1[k * CD + cc], acc[cc]);
        k++;
    }

    #pragma unroll
    for (int c0 = 0; c0 < CD; c0 += 8) {
        f16x8 o;
        #pragma unroll
        for (int j = 0; j < 8; j++) {
            int cc = c0 + j;
            float sc = g1[cc] * rsqrtf(v1[cc] + EPSV);
            float y = (acc[cc] - m1[cc] + b1[cc]) * sc + be1[cc];
            o[j] = (f16)fmaxf(y, 0.f);
        }
        *(f16x8*)(x1 + (size_t)r * CD + c0) = o;
    }
}

// ---- conv v11 (verbatim, proven 119.5us / FETCH 50.8MB / passed x3):
// seven structural variants (occupancy/barriers/drains/locality/depth/coop)
// all landed 118-145us -> conv is at its structural floor for this
// decomposition; do not touch without new counter evidence.
#define MFMA3216(a, b, c) __builtin_amdgcn_mfma_f32_32x32x16_f16(a, b, c, 0, 0, 0)

#define VMW_(n) asm volatile("s_waitcnt vmcnt(" #n ")" ::: "memory")
#define VMW(n) VMW_(n)

#define CONV_BODY(K, WN)                                                        \
  {                                                                             \
    VMW(WN);                                                                    \
    __builtin_amdgcn_s_barrier();                                               \
    asm volatile("" ::: "memory");                                              \
    if ((K) + 1 < KOFF) {                                                       \
      _Pragma("unroll")                                                         \
      for (int it = 0; it < 2; it++) {                                          \
        const char* gp = (const char*)wT + ((size_t)((K) + 1) * 8192            \
                          + it * 4096 + tid * 16);                              \
        char* lp = (char*)bbuf + (((K) + 1) & 1) * 8192 + it * 4096 + wv * 1024;\
        GLDS16(gp, lp);                                                         \
      }                                                                         \
      const int aidx = ((K) + 1 == 13) ? row : idxN;                            \
      const char* ap = ((aidx >= 0)                                             \
          ? (const char*)xin + (size_t)aidx * 128                               \
          : (const char*)zr) + g * 16;                                          \
      _Pragma("unroll")                                                         \
      for (int ks = 0; ks < 4; ks++)                                            \
        aF[((K) + 1) & 1][ks] = *(const f16x8*)(ap + ks * 32);                  \
    }                                                                           \
    int iwN = idxN;                                                             \
    if ((K) + 2 < KOFF)                                                         \
      iwN = nbr[(size_t)((K) + 2) * NV + row];                                  \
    asm volatile("" ::: "memory");                                              \
    __builtin_amdgcn_s_setprio(1);                                              \
    _Pragma("unroll")                                                           \
    for (int ks = 0; ks < 4; ks++) {                                            \
      const char* bp = (const char*)bbuf + ((K) & 1) * 8192                     \
                       + (2 * ks + g) * 1024;                                   \
      f16x8 b0 = *(const f16x8*)(bp + ml * 16);                                 \
      f16x8 b1 = *(const f16x8*)(bp + 512 + ml * 16);                           \
      acc[0] = MFMA3216(aF[(K) & 1][ks], b0, acc[0]);                           \
      acc[1] = MFMA3216(aF[(K) & 1][ks], b1, acc[1]);                           \
    }                                                                           \
    __builtin_amdgcn_s_setprio(0);                                              \
    idxN = iwN;                                                                 \
  }

static_assert(NV % 128 == 0, "grid must tile exactly");

template <bool OUTF32>
__global__ __launch_bounds__(256, 5) void k_conv(
        const f16* __restrict__ xin, const f16* __restrict__ wT,
        const int* __restrict__ nbr, const f16* __restrict__ zr,
        const float* __restrict__ bb, const float* __restrict__ gg,
        const float* __restrict__ bee, const float* __restrict__ mm,
        const float* __restrict__ vv, void* __restrict__ outp) {
    // 16 KB: B double-buffer [2][8192] during the loop; same bytes are the
    // epilogue transpose scratch after the last MFMA.
    __shared__ __align__(16) unsigned char smem[16384];
    unsigned char* bbuf = smem;
    unsigned char* sS = smem;

    const int tid = threadIdx.x;
    const int lane = tid & 63;
    const int wv = tid >> 6;
    const int g = lane >> 5;
    const int ml = lane & 31;
    // bijective XCD-chunked swizzle: grid 3125 = 8*390 + 5; first 5 XCDs get
    // 391 contiguous blocks, rest 390 -> each XCD walks its own rank window.
    int bid;
    {
        int x = blockIdx.x & 7, j = blockIdx.x >> 3;
        bid = (x < 5 ? x * 391 : 5 * 391 + (x - 5) * 390) + j;
    }
    const int vbase = bid * 128;
    const int row = vbase + wv * 32 + ml;     // this lane's A-row (rank space)

    f32x16 acc[2];
    #pragma unroll
    for (int b = 0; b < 2; b++) acc[b] = (f32x16)(0.f);

    f16x8 aF[2][4];
    int idxN;

    // prologue: stage B(0); fence; A(0) -> aF[0]; idx(1) -> idxN; fence
    #pragma unroll
    for (int it = 0; it < 2; it++) {
        const char* gp = (const char*)wT + ((size_t)it * 4096 + tid * 16);
        char* lp = (char*)bbuf + it * 4096 + wv * 1024;
        GLDS16(gp, lp);
    }
    asm volatile("" ::: "memory");
    {
        int iw0 = nbr[row];
        idxN = nbr[(size_t)NV + row];
        const char* ap = ((iw0 >= 0)
            ? (const char*)xin + (size_t)iw0 * 128
            : (const char*)zr) + g * 16;
        #pragma unroll
        for (int ks = 0; ks < 4; ks++)
            aF[0][ks] = *(const f16x8*)(ap + ks * 32);
    }
    asm volatile("" ::: "memory");

    CONV_BODY(0, 6)
    CONV_BODY(1, 5)
    CONV_BODY(2, 5)
    CONV_BODY(3, 5)
    CONV_BODY(4, 5)
    CONV_BODY(5, 5)
    CONV_BODY(6, 5)
    CONV_BODY(7, 5)
    CONV_BODY(8, 5)
    CONV_BODY(9, 5)
    CONV_BODY(10, 5)
    CONV_BODY(11, 5)
    CONV_BODY(12, 5)
    CONV_BODY(13, 5)
    CONV_BODY(14, 5)
    CONV_BODY(15, 5)
    CONV_BODY(16, 5)
    CONV_BODY(17, 5)
    CONV_BODY(18, 5)
    CONV_BODY(19, 5)
    CONV_BODY(20, 5)
    CONV_BODY(21, 5)
    CONV_BODY(22, 5)
    CONV_BODY(23, 5)
    CONV_BODY(24, 5)
    CONV_BODY(25, 5)
    CONV_BODY(26, 4)

    // epilogue: BN+ReLU -> LDS transpose -> vectorized stores
    if (!OUTF32) {
        __syncthreads();
        #pragma unroll
        for (int nt = 0; nt < 2; nt++) {
            int cn = nt * 32 + ml;
            float sc = gg[cn] * rsqrtf(vv[cn] + EPSV);
            float sh = (bb[cn] - mm[cn]) * sc + bee[cn];
            #pragma unroll
            for (int r = 0; r < 16; r++) {
                int rowl = wv * 32 + (r & 3) + 8 * (r >> 2) + 4 * g;
                float y = fmaxf(acc[nt][r] * sc + sh, 0.f);
                *(f16*)(sS + rowl * 128 + cn * 2) = (f16)y;
            }
        }
        __syncthreads();
        char* gb = (char*)outp + (size_t)vbase * 128;
        #pragma unroll
        for (int it = 0; it < 4; it++) {
            int s = it * 256 + tid;
            *(float4*)(gb + s * 16) = *(const float4*)(sS + s * 16);
        }
    } else {
        // scatter rows back to ORIGINAL voxel order via nbr[13] (orig index)
        #pragma unroll 1
        for (int p = 0; p < 2; p++) {
            __syncthreads();
            if ((wv >> 1) == p) {
                int lw = wv & 1;
                #pragma unroll
                for (int nt = 0; nt < 2; nt++) {
                    int cn = nt * 32 + ml;
                    float sc = gg[cn] * rsqrtf(vv[cn] + EPSV);
                    float sh = (bb[cn] - mm[cn]) * sc + bee[cn];
                    #pragma unroll
                    for (int r = 0; r < 16; r++) {
                        int rowl = lw * 32 + (r & 3) + 8 * (r >> 2) + 4 * g;
                        float y = fmaxf(acc[nt][r] * sc + sh, 0.f);
                        *(float*)(sS + rowl * 256 + cn * 4) = y;
                    }
                }
            }
            __syncthreads();
            #pragma unroll
            for (int it = 0; it < 4; it++) {
                int s = it * 256 + tid;
                int o = nbr[13 * (size_t)NV + vbase + p * 64 + (s >> 4)];
                *(float4*)((char*)outp + (size_t)o * 256 + (s & 15) * 16)
                    = *(const float4*)(sS + s * 16);
            }
        }
    }
}

extern "C" void kernel_launch(void* const* d_in, const int* in_sizes, int n_in,
                              void* d_out, int out_size, void* d_ws, size_t ws_size,
                              hipStream_t stream) {
    (void)in_sizes; (void)n_in; (void)out_size; (void)ws_size;
    const float* feats = (const float*)d_in[0];
    const int4* coords = (const int4*)d_in[1];
    const float* w1 = (const float*)d_in[2];
    const float* b1 = (const float*)d_in[3];
    const float* g1 = (const float*)d_in[4];
    const float* be1 = (const float*)d_in[5];
    const float* m1 = (const float*)d_in[6];
    const float* v1 = (const float*)d_in[7];
    const float* w2 = (const float*)d_in[8];
    const float* b2 = (const float*)d_in[9];
    const float* g2 = (const float*)d_in[10];
    const float* be2 = (const float*)d_in[11];
    const float* m2 = (const float*)d_in[12];
    const float* v2 = (const float*)d_in[13];
    const float* w3 = (const float*)d_in[14];
    const float* b3 = (const float*)d_in[15];
    const float* g3 = (const float*)d_in[16];
    const float* be3 = (const float*)d_in[17];
    const float* m3 = (const float*)d_in[18];
    const float* v3 = (const float*)d_in[19];

    char* ws = (char*)d_ws;
    int* nbr  = (int*)(ws + OFF_NBR);
    f16* x1   = (f16*)(ws + OFF_X1);
    f16* x2   = (f16*)(ws + OFF_X2);
    int* tab  = (int*)(ws + OFF_TAB);
    int* hist = (int*)(ws + OFF_HIST);
    int* bsum = (int*)(ws + OFF_BSUM);
    float* fs = (float*)(ws + OFF_FS);
    f16* w2t  = (f16*)(ws + OFF_W2T);
    f16* w3t  = (f16*)(ws + OFF_W3T);
    f16* zrow = (f16*)(ws + OFF_ZERO);

    k_init<<<4096, 256, 0, stream>>>(w2, w3, tab, w2t, w3t, zrow, hist);
    k_hist<<<(NV + 255) / 256, 256, 0, stream>>>(coords, hist);
    k_scan1<<<NCELL / 1024, 1024, 0, stream>>>(hist, bsum);
    k_scan2<<<1, 64, 0, stream>>>(bsum);
    k_rank<<<(NV + 255) / 256, 256, 0, stream>>>(coords, feats, hist, bsum, tab, nbr, fs);
    k_nbrl1<<<(NV + 255) / 256, 256, 0, stream>>>(coords, tab, fs, nbr,
                                                  w1, b1, g1, be1, m1, v1, x1);
    const int convgrid = NV / 128;  // 3125, exact
    k_conv<false><<<convgrid, 256, 0, stream>>>(x1, w2t, nbr, zrow, b2, g2, be2, m2, v2, (void*)x2);
    k_conv<true><<<convgrid, 256, 0, stream>>>(x2, w3t, nbr, zrow, b3, g3, be3, m3, v3, d_out);
}